// Round 1
// baseline (32.425 us; speedup 1.0000x reference)
//
#include <hip/hip_runtime.h>
#include <math.h>

#define C_N 512
#define S_N 256
#define NN  16
#define DP1 9      // d+1
#define KT  40     // uniformization series terms

// Kernel A: per-character hyperbolic distance -> t[c]; also zero the output.
__global__ __launch_bounds__(512) void prep_kernel(
    const float* __restrict__ X, const int* __restrict__ ip,
    float* __restrict__ t_ws, float* __restrict__ out) {
    int c = threadIdx.x;
    if (c == 0) out[0] = 0.0f;
    if (c < C_N) {
        int i0 = ip[0];
        const float* xc = X + c * DP1;
        const float* xi = X + i0 * DP1;
        float inner = -xi[0] * xc[0];
        #pragma unroll
        for (int d = 1; d < DP1; ++d) inner += xc[d] * xi[d];
        float u = fmaxf(-inner, 1.0f + 1e-6f);   // RHO = 1
        float dist = acoshf(u);
        t_ws[c] = 0.5f * dist;
    }
}

// Kernel B: one block per site s. Uniformization row-power tables in LDS,
// then sweep all c computing the 4 needed expm entries + log accumulation.
__global__ __launch_bounds__(256) void loglik_kernel(
    const float* __restrict__ Q, const int* __restrict__ ch,
    const int* __restrict__ ip, const float* __restrict__ t_ws,
    float* __restrict__ out) {
    int s = blockIdx.x;
    int tid = threadIdx.x;

    __shared__ float A[NN][NN];
    __shared__ float w0[KT][NN];   // e_0^T A^k
    __shared__ float w1[KT][NN];   // e_si^T A^k
    __shared__ float lam_sh;
    __shared__ int   si_sh;
    __shared__ float recip[KT + 1];
    __shared__ float red[4];

    const float* Qs = Q + s * NN * NN;
    int i0 = ip[0];

    if (tid == 0) {
        float lam = 1e-20f;
        for (int j = 0; j < NN; ++j) lam = fmaxf(lam, -Qs[j * NN + j]);
        lam_sh = lam;
        si_sh  = ch[i0 * S_N + s];
    }
    if (tid <= KT) recip[tid] = (tid == 0) ? 0.0f : 1.0f / (float)tid;
    __syncthreads();
    float lam = lam_sh;
    int   si  = si_sh;

    // A = I + Q/lam (stochastic, nonnegative)
    {
        int r = tid >> 4, cc = tid & 15;
        A[r][cc] = Qs[tid] / lam + (r == cc ? 1.0f : 0.0f);
    }
    if (tid < NN) {
        w0[0][tid] = (tid == 0)  ? 1.0f : 0.0f;
        w1[0][tid] = (tid == si) ? 1.0f : 0.0f;
    }
    __syncthreads();

    // Row-power iteration: w_{k}[j] = sum_m w_{k-1}[m] * A[m][j]
    for (int k = 1; k < KT; ++k) {
        if (tid < NN) {
            float acc = 0.0f;
            #pragma unroll
            for (int m = 0; m < NN; ++m) acc += w0[k - 1][m] * A[m][tid];
            w0[k][tid] = acc;
        } else if (tid < 2 * NN) {
            int j = tid - NN;
            float acc = 0.0f;
            #pragma unroll
            for (int m = 0; m < NN; ++m) acc += w1[k - 1][m] * A[m][j];
            w1[k][j] = acc;
        }
        __syncthreads();
    }

    // Sweep characters: 4 Poisson-weighted series evaluations + log
    float partial = 0.0f;
    for (int c = tid; c < C_N; c += 256) {
        if (c == i0) continue;
        float t = t_ws[c];
        float x = lam * t;
        int sj  = ch[c * S_N + s];
        float p = expf(-x);           // Poisson weight k=0
        float a0 = 0.f, a1 = 0.f, a2 = 0.f, a3 = 0.f;
        #pragma unroll 8
        for (int k = 0; k < KT; ++k) {
            a0 = fmaf(p, w0[k][si], a0);   // P[0, si]
            a1 = fmaf(p, w0[k][sj], a1);   // P[0, sj]
            a2 = fmaf(p, w1[k][si], a2);   // P[si, si]
            a3 = fmaf(p, w1[k][sj], a3);   // P[si, sj]
            p *= x * recip[k + 1];
        }
        bool same = (si == sj) && (si != 0);
        float cur = 0.0625f * (a0 * a1 + (same ? a2 * a3 : 0.0f));
        partial += logf(cur);
    }

    // wave + block reduction, one atomic per block
    #pragma unroll
    for (int off = 32; off > 0; off >>= 1)
        partial += __shfl_down(partial, off, 64);
    if ((tid & 63) == 0) red[tid >> 6] = partial;
    __syncthreads();
    if (tid == 0) {
        atomicAdd(out, red[0] + red[1] + red[2] + red[3]);
    }
}

extern "C" void kernel_launch(void* const* d_in, const int* in_sizes, int n_in,
                              void* d_out, int out_size, void* d_ws, size_t ws_size,
                              hipStream_t stream) {
    const float* X  = (const float*)d_in[0];   // (C, 9) f32
    const float* Q  = (const float*)d_in[1];   // (S, 16, 16) f32
    const int*   ch = (const int*)d_in[2];     // (C, S) i32
    const int*   ip = (const int*)d_in[3];     // scalar i
    float* out  = (float*)d_out;
    float* t_ws = (float*)d_ws;                // C floats

    prep_kernel<<<1, 512, 0, stream>>>(X, ip, t_ws, out);
    loglik_kernel<<<S_N, 256, 0, stream>>>(Q, ch, ip, t_ws, out);
}

// Round 2
// 14.344 us; speedup vs baseline: 2.2605x; 2.2605x over previous
//
#include <hip/hip_runtime.h>
#include <math.h>

#define C_N 512
#define S_N 256
#define NN  16
#define DP1 9      // d+1
#define KT  24     // uniformization series terms (x = lam*t <~ 2.3; tail < 1e-11 rel)

// One block per site s. Wave 0 builds the uniformization row-power tables
// entirely in registers (shfl recursion, no barriers), writes them to LDS;
// then all 256 threads sweep characters (t computed inline) and the block
// partial goes to partials[s]. No atomics anywhere.
__global__ __launch_bounds__(256) void site_kernel(
    const float* __restrict__ X, const float* __restrict__ Q,
    const int* __restrict__ ch, const int* __restrict__ ip,
    float* __restrict__ partials)
{
    const int s   = blockIdx.x;
    const int tid = threadIdx.x;

    __shared__ float w0[KT][NN];   // e_0^T   A^k
    __shared__ float w1[KT][NN];   // e_si^T  A^k
    __shared__ float lam_sh;
    __shared__ float red[4];

    const float* __restrict__ Qs = Q + s * NN * NN;
    const int i0 = ip[0];
    const int si = ch[i0 * S_N + s];

    if (tid < 32) {
        const int j = tid & 15;
        // lam = max_j -Q[j][j], reduced across the 16 lanes of each half-group
        float dmax = -Qs[j * NN + j];
        #pragma unroll
        for (int off = 8; off; off >>= 1)
            dmax = fmaxf(dmax, __shfl_xor(dmax, off, 64));
        const float lam = dmax;
        if (tid == 0) lam_sh = lam;
        const float rl = 1.0f / lam;

        // lane j holds column j of A = I + Q/lam (both 16-lane groups load it)
        float a[NN];
        #pragma unroll
        for (int m = 0; m < NN; ++m)
            a[m] = Qs[m * NN + j] * rl + (m == j ? 1.0f : 0.0f);

        const int grp  = tid >> 4;          // 0: row e_0 path, 1: row e_si path
        const int base = grp << 4;
        float w = (grp == 0) ? (j == 0 ? 1.0f : 0.0f)
                             : (j == si ? 1.0f : 0.0f);
        if (grp == 0) w0[0][j] = w; else w1[0][j] = w;

        // register recursion: w_new[j] = sum_m w[m] * A[m][j]; no barriers
        #pragma unroll
        for (int k = 1; k < KT; ++k) {
            float wn = 0.0f;
            #pragma unroll
            for (int m = 0; m < NN; ++m)
                wn = fmaf(__shfl(w, base + m, 64), a[m], wn);
            w = wn;
            if (grp == 0) w0[k][j] = w; else w1[k][j] = w;
        }
    }
    __syncthreads();

    const float lam = lam_sh;
    const float* __restrict__ xi = X + i0 * DP1;
    const float x0i = xi[0];
    float vi[8];
    #pragma unroll
    for (int d = 0; d < 8; ++d) vi[d] = xi[1 + d];

    float partial = 0.0f;
    #pragma unroll
    for (int cc = 0; cc < 2; ++cc) {
        const int c = tid + cc * 256;
        if (c == i0) continue;
        // hyperbolic distance -> t (inline; RHO = 1)
        const float* __restrict__ xc = X + c * DP1;
        float inner = -x0i * xc[0];
        #pragma unroll
        for (int d = 0; d < 8; ++d) inner = fmaf(vi[d], xc[1 + d], inner);
        const float u = fmaxf(-inner, 1.0f + 1e-6f);
        const float dist = __logf(u + __fsqrt_rn(fmaf(u, u, -1.0f)));  // acosh
        const float x = lam * (0.5f * dist);

        const int sj = ch[c * S_N + s];
        float p  = __expf(-x);               // Poisson weight k=0
        float a0 = 0.f, a1 = 0.f, a2 = 0.f, a3 = 0.f;
        #pragma unroll
        for (int k = 0; k < KT; ++k) {
            a0 = fmaf(p, w0[k][si], a0);     // P[0,  si]
            a1 = fmaf(p, w0[k][sj], a1);     // P[0,  sj]
            a2 = fmaf(p, w1[k][si], a2);     // P[si, si]
            a3 = fmaf(p, w1[k][sj], a3);     // P[si, sj]
            p *= x * (1.0f / (float)(k + 1));  // constant-folded reciprocal
        }
        const bool same = (si == sj) && (si != 0);
        const float cur = 0.0625f * (a0 * a1 + (same ? a2 * a3 : 0.0f));
        partial += __logf(cur);
    }

    // wave + block reduction -> partials[s]
    #pragma unroll
    for (int off = 32; off; off >>= 1)
        partial += __shfl_down(partial, off, 64);
    if ((tid & 63) == 0) red[tid >> 6] = partial;
    __syncthreads();
    if (tid == 0) partials[s] = red[0] + red[1] + red[2] + red[3];
}

// Deterministic final reduction of 256 site partials -> out[0].
__global__ __launch_bounds__(256) void reduce_kernel(
    const float* __restrict__ partials, float* __restrict__ out)
{
    const int tid = threadIdx.x;
    __shared__ float red[4];
    float v = partials[tid];
    #pragma unroll
    for (int off = 32; off; off >>= 1)
        v += __shfl_down(v, off, 64);
    if ((tid & 63) == 0) red[tid >> 6] = v;
    __syncthreads();
    if (tid == 0) out[0] = red[0] + red[1] + red[2] + red[3];
}

extern "C" void kernel_launch(void* const* d_in, const int* in_sizes, int n_in,
                              void* d_out, int out_size, void* d_ws, size_t ws_size,
                              hipStream_t stream) {
    const float* X  = (const float*)d_in[0];   // (C, 9)  f32
    const float* Q  = (const float*)d_in[1];   // (S,16,16) f32
    const int*   ch = (const int*)d_in[2];     // (C, S) i32
    const int*   ip = (const int*)d_in[3];     // scalar i
    float* out      = (float*)d_out;
    float* partials = (float*)d_ws;            // S_N floats

    site_kernel<<<S_N, 256, 0, stream>>>(X, Q, ch, ip, partials);
    reduce_kernel<<<1, 256, 0, stream>>>(partials, out);
}

// Round 3
// 11.901 us; speedup vs baseline: 2.7244x; 1.2052x over previous
//
#include <hip/hip_runtime.h>
#include <math.h>

#define C_N 512
#define S_N 256
#define NN  16
#define DP1 9      // d+1
#define KT  16     // uniformization terms: x = lam*t <= ~1.7, tail(16) < 1e-9 rel
#define KTP 20     // padded row length: 80B rows stay 16B-aligned, spread banks

// One block per site s. Waves 0/1 build the two row-power tables in parallel
// (4x16 lane decomposition, shfl_xor reduce, no barriers inside); tables are
// stored TRANSPOSED (state-major, k contiguous) so the character sweep reads
// them with ds_read_b128. Waves 2/3 overlap their distance computation with
// the table build.
__global__ __launch_bounds__(256) void site_kernel(
    const float* __restrict__ X, const float* __restrict__ Q,
    const int* __restrict__ ch, const int* __restrict__ ip,
    float* __restrict__ partials)
{
    const int s   = blockIdx.x;
    const int tid = threadIdx.x;
    const int wid = tid >> 6;

    __shared__ __align__(16) float w0T[NN][KTP];   // (e_0^T  A^k)[j] at w0T[j][k]
    __shared__ __align__(16) float w1T[NN][KTP];   // (e_si^T A^k)[j] at w1T[j][k]
    __shared__ float lam_sh;
    __shared__ float red[4];

    const float* __restrict__ Qs = Q + s * NN * NN;
    const int i0 = ip[0];
    const int si = ch[i0 * S_N + s];

    // ---- table build: wave 0 -> w0T, wave 1 -> w1T (parallel on 2 SIMDs) ----
    if (wid < 2) {
        const int lane = tid & 63;
        const int j = lane & 15;          // output state
        const int q = lane >> 4;          // m-chunk 0..3
        // lam = max_j -Q[j][j], butterfly over the 16 j-lanes (replicated)
        float dmax = -Qs[j * NN + j];
        #pragma unroll
        for (int off = 1; off < 16; off <<= 1)
            dmax = fmaxf(dmax, __shfl_xor(dmax, off, 64));
        const float lam = dmax;
        if (tid == 0) lam_sh = lam;
        const float rl = 1.0f / lam;

        // lane (q,j) holds A[4q+m][j] for m=0..3 ;  A = I + Q/lam
        float a[4];
        #pragma unroll
        for (int m = 0; m < 4; ++m) {
            const int r = 4 * q + m;
            a[m] = Qs[r * NN + j] * rl + (r == j ? 1.0f : 0.0f);
        }

        float (*WT)[KTP] = (wid == 0) ? w0T : w1T;
        const int tgt = (wid == 0) ? 0 : si;
        float w = (j == tgt) ? 1.0f : 0.0f;   // w_0[j], replicated across q
        if (q == 0) WT[j][0] = w;

        #pragma unroll
        for (int k = 1; k < KT; ++k) {
            float acc = 0.0f;
            #pragma unroll
            for (int m = 0; m < 4; ++m)
                acc = fmaf(__shfl(w, 4 * q + m, 64), a[m], acc);
            acc += __shfl_xor(acc, 16, 64);
            acc += __shfl_xor(acc, 32, 64);
            w = acc;                          // replicated across q again
            if (q == 0) WT[j][k] = w;
        }
    }

    // ---- per-character distance (independent of tables; overlaps build) ----
    const float* __restrict__ xi = X + i0 * DP1;
    const float x0i = xi[0];
    float vi[8];
    #pragma unroll
    for (int d = 0; d < 8; ++d) vi[d] = xi[1 + d];

    float x_c[2]; int sj_c[2]; bool ok_c[2];
    #pragma unroll
    for (int cc = 0; cc < 2; ++cc) {
        const int c = tid + cc * 256;
        ok_c[cc] = (c != i0);
        const float* __restrict__ xc = X + c * DP1;
        float inner = -x0i * xc[0];
        #pragma unroll
        for (int d = 0; d < 8; ++d) inner = fmaf(vi[d], xc[1 + d], inner);
        const float u = fmaxf(-inner, 1.0f + 1e-6f);
        const float dist = __logf(u + __fsqrt_rn(fmaf(u, u, -1.0f)));  // acosh
        x_c[cc]  = 0.5f * dist;            // multiply by lam after barrier
        sj_c[cc] = ch[c * S_N + s];
    }
    __syncthreads();
    const float lam = lam_sh;

    // ---- character sweep: 4 Poisson-weighted series via b128 table reads ----
    float partial = 0.0f;
    #pragma unroll
    for (int cc = 0; cc < 2; ++cc) {
        const float x  = lam * x_c[cc];
        const int   sj = sj_c[cc];
        const float4* __restrict__ u0p = (const float4*)&w0T[si][0];
        const float4* __restrict__ u1p = (const float4*)&w0T[sj][0];
        const float4* __restrict__ u2p = (const float4*)&w1T[si][0];
        const float4* __restrict__ u3p = (const float4*)&w1T[sj][0];
        float p = __expf(-x);
        float a0 = 0.f, a1 = 0.f, a2 = 0.f, a3 = 0.f;
        #pragma unroll
        for (int kb = 0; kb < 4; ++kb) {
            const float4 f0 = u0p[kb], f1 = u1p[kb], f2 = u2p[kb], f3 = u3p[kb];
            #define STEP(K, CMP)                                   \
                a0 = fmaf(p, f0.CMP, a0);                          \
                a1 = fmaf(p, f1.CMP, a1);                          \
                a2 = fmaf(p, f2.CMP, a2);                          \
                a3 = fmaf(p, f3.CMP, a3);                          \
                p *= x * (1.0f / (float)((K) + 1));
            STEP(4 * kb + 0, x)
            STEP(4 * kb + 1, y)
            STEP(4 * kb + 2, z)
            STEP(4 * kb + 3, w)
            #undef STEP
        }
        const bool same = (si == sj) && (si != 0);
        const float cur = 0.0625f * (a0 * a1 + (same ? a2 * a3 : 0.0f));
        if (ok_c[cc]) partial += __logf(cur);
    }

    // ---- wave + block reduction -> partials[s] ----
    #pragma unroll
    for (int off = 32; off; off >>= 1)
        partial += __shfl_down(partial, off, 64);
    if ((tid & 63) == 0) red[tid >> 6] = partial;
    __syncthreads();
    if (tid == 0) partials[s] = red[0] + red[1] + red[2] + red[3];
}

// Deterministic final reduction of 256 site partials -> out[0].
__global__ __launch_bounds__(256) void reduce_kernel(
    const float* __restrict__ partials, float* __restrict__ out)
{
    const int tid = threadIdx.x;
    __shared__ float red[4];
    float v = partials[tid];
    #pragma unroll
    for (int off = 32; off; off >>= 1)
        v += __shfl_down(v, off, 64);
    if ((tid & 63) == 0) red[tid >> 6] = v;
    __syncthreads();
    if (tid == 0) out[0] = red[0] + red[1] + red[2] + red[3];
}

extern "C" void kernel_launch(void* const* d_in, const int* in_sizes, int n_in,
                              void* d_out, int out_size, void* d_ws, size_t ws_size,
                              hipStream_t stream) {
    const float* X  = (const float*)d_in[0];   // (C, 9)  f32
    const float* Q  = (const float*)d_in[1];   // (S,16,16) f32
    const int*   ch = (const int*)d_in[2];     // (C, S) i32
    const int*   ip = (const int*)d_in[3];     // scalar i
    float* out      = (float*)d_out;
    float* partials = (float*)d_ws;            // S_N floats

    site_kernel<<<S_N, 256, 0, stream>>>(X, Q, ch, ip, partials);
    reduce_kernel<<<1, 256, 0, stream>>>(partials, out);
}

// Round 4
// 11.833 us; speedup vs baseline: 2.7401x; 1.0058x over previous
//
#include <hip/hip_runtime.h>
#include <math.h>

#define C_N 512
#define S_N 256
#define NN  16
#define DP1 9      // d+1
#define KT  16     // series terms: x = lam*t <= ~1.7, tail(16) < 1e-9 rel
#define KTP 20     // padded row length: 80B rows, 16B-aligned, bank-spread

// Tables stored TRANSPOSED and PRE-DIVIDED by k!:
//   wh0T[j][k] = (e_0^T  A^k)[j] / k!     wh1T[j][k] = (e_si^T A^k)[j] / k!
// Then P[r][j] = e^{-x} * sum_k wh[j][k] x^k  (Horner), and e^{-x} factors
// out of the likelihood product: log(cur) = -2x + log(pi*(H0*H1 + s*H2*H3)).
__global__ __launch_bounds__(512) void site_kernel(
    const float* __restrict__ X, const float* __restrict__ Q,
    const int* __restrict__ ch, const int* __restrict__ ip,
    float* __restrict__ partials)
{
    const int s   = blockIdx.x;
    const int tid = threadIdx.x;
    const int wid = tid >> 6;

    __shared__ __align__(16) float wh0T[NN][KTP];
    __shared__ __align__(16) float wh1T[NN][KTP];
    __shared__ float lam_sh;
    __shared__ float red[8];

    const float* __restrict__ Qs = Q + s * NN * NN;
    const int i0 = ip[0];
    const int si = ch[i0 * S_N + s];

    // ---- table build: wave 0 -> wh0T, wave 1 -> wh1T (parallel SIMDs) ----
    if (wid < 2) {
        const int lane = tid & 63;
        const int j = lane & 15;          // output state
        const int q = lane >> 4;          // m-chunk 0..3
        float dmax = -Qs[j * NN + j];
        #pragma unroll
        for (int off = 1; off < 16; off <<= 1)
            dmax = fmaxf(dmax, __shfl_xor(dmax, off, 64));
        const float lam = dmax;
        if (tid == 0) lam_sh = lam;
        const float rl = 1.0f / lam;

        // lane (q,j) holds A[4q+m][j], m=0..3 ; A = I + Q/lam
        float a[4];
        #pragma unroll
        for (int m = 0; m < 4; ++m) {
            const int r = 4 * q + m;
            a[m] = Qs[r * NN + j] * rl + (r == j ? 1.0f : 0.0f);
        }

        constexpr float IF[KT] = {
            1.f, 1.f, 5.0e-1f, 1.6666667e-1f, 4.1666667e-2f, 8.3333333e-3f,
            1.3888889e-3f, 1.9841270e-4f, 2.4801587e-5f, 2.7557319e-6f,
            2.7557319e-7f, 2.5052108e-8f, 2.0876757e-9f, 1.6059044e-10f,
            1.1470746e-11f, 7.6471637e-13f };

        float (*WT)[KTP] = (wid == 0) ? wh0T : wh1T;
        const int tgt = (wid == 0) ? 0 : si;
        float w = (j == tgt) ? 1.0f : 0.0f;   // replicated across q
        if (q == 0) WT[j][0] = w;

        #pragma unroll
        for (int k = 1; k < KT; ++k) {
            float acc = 0.0f;
            #pragma unroll
            for (int m = 0; m < 4; ++m)
                acc = fmaf(__shfl(w, 4 * q + m, 64), a[m], acc);
            acc += __shfl_xor(acc, 16, 64);
            acc += __shfl_xor(acc, 32, 64);
            w = acc;                          // replicated across q
            if (q == 0) WT[j][k] = w * IF[k];
        }
    }

    // ---- own-character distance (overlaps table build) ----
    const float* __restrict__ xi = X + i0 * DP1;
    const float x0i = xi[0];
    float vi[8];
    #pragma unroll
    for (int d = 0; d < 8; ++d) vi[d] = xi[1 + d];

    const int c = tid;                      // 512 threads, 1 char each
    const bool ok = (c != i0);
    const float* __restrict__ xc = X + c * DP1;
    float inner = -x0i * xc[0];
    #pragma unroll
    for (int d = 0; d < 8; ++d) inner = fmaf(vi[d], xc[1 + d], inner);
    const float u = fmaxf(-inner, 1.0f + 1e-6f);
    const float dist = __logf(u + __fsqrt_rn(fmaf(u, u, -1.0f)));  // acosh
    const float thalf = 0.5f * dist;
    const int sj = ch[c * S_N + s];

    __syncthreads();
    const float x = lam_sh * thalf;

    // ---- 4 Horner evaluations over b128 table reads ----
    float4 f0[4], f1[4], f2[4], f3[4];
    {
        const float4* __restrict__ u0p = (const float4*)&wh0T[si][0];
        const float4* __restrict__ u1p = (const float4*)&wh0T[sj][0];
        const float4* __restrict__ u2p = (const float4*)&wh1T[si][0];
        const float4* __restrict__ u3p = (const float4*)&wh1T[sj][0];
        #pragma unroll
        for (int kb = 0; kb < 4; ++kb) {
            f0[kb] = u0p[kb]; f1[kb] = u1p[kb];
            f2[kb] = u2p[kb]; f3[kb] = u3p[kb];
        }
    }
    const float* c0 = (const float*)f0;
    const float* c1 = (const float*)f1;
    const float* c2 = (const float*)f2;
    const float* c3 = (const float*)f3;
    float h0 = c0[KT - 1], h1 = c1[KT - 1], h2 = c2[KT - 1], h3 = c3[KT - 1];
    #pragma unroll
    for (int k = KT - 2; k >= 0; --k) {
        h0 = fmaf(h0, x, c0[k]);
        h1 = fmaf(h1, x, c1[k]);
        h2 = fmaf(h2, x, c2[k]);
        h3 = fmaf(h3, x, c3[k]);
    }
    const bool same = (si == sj) && (si != 0);
    const float prod = h0 * h1 + (same ? h2 * h3 : 0.0f);
    float partial = ok ? (__logf(0.0625f * prod) - 2.0f * x) : 0.0f;

    // ---- wave + block reduction -> partials[s] ----
    #pragma unroll
    for (int off = 32; off; off >>= 1)
        partial += __shfl_down(partial, off, 64);
    if ((tid & 63) == 0) red[wid] = partial;
    __syncthreads();
    if (tid == 0) {
        float acc = 0.0f;
        #pragma unroll
        for (int wv = 0; wv < 8; ++wv) acc += red[wv];
        partials[s] = acc;
    }
}

// Deterministic final reduction of 256 site partials -> out[0].
__global__ __launch_bounds__(256) void reduce_kernel(
    const float* __restrict__ partials, float* __restrict__ out)
{
    const int tid = threadIdx.x;
    __shared__ float red[4];
    float v = partials[tid];
    #pragma unroll
    for (int off = 32; off; off >>= 1)
        v += __shfl_down(v, off, 64);
    if ((tid & 63) == 0) red[tid >> 6] = v;
    __syncthreads();
    if (tid == 0) out[0] = red[0] + red[1] + red[2] + red[3];
}

extern "C" void kernel_launch(void* const* d_in, const int* in_sizes, int n_in,
                              void* d_out, int out_size, void* d_ws, size_t ws_size,
                              hipStream_t stream) {
    const float* X  = (const float*)d_in[0];   // (C, 9)  f32
    const float* Q  = (const float*)d_in[1];   // (S,16,16) f32
    const int*   ch = (const int*)d_in[2];     // (C, S) i32
    const int*   ip = (const int*)d_in[3];     // scalar i
    float* out      = (float*)d_out;
    float* partials = (float*)d_ws;            // S_N floats

    site_kernel<<<S_N, 512, 0, stream>>>(X, Q, ch, ip, partials);
    reduce_kernel<<<1, 256, 0, stream>>>(partials, out);
}